// Round 16
// baseline (657.299 us; speedup 1.0000x reference)
//
#include <hip/hip_runtime.h>

#define TT 4
#define NN 20000
#define EE 320000
#define NZ 340000
#define NBKT 2500  // NN/8 per XCD bucket
#define SCB 2048   // scatter blocks in k_susr
#define CNTB 2048  // bucketed count blocks in k_setup

typedef __attribute__((ext_vector_type(8))) __bf16 bf16x8;
typedef __attribute__((ext_vector_type(16))) float f32x16;

__device__ __forceinline__ unsigned short f2bf(float f) {
    unsigned int u = __float_as_uint(f);
    u = (u + 0x7FFFu + ((u >> 16) & 1u)) >> 16;
    return (unsigned short)u;
}
__device__ __forceinline__ float bf2f(unsigned short h) {
    return __uint_as_float(((unsigned int)h) << 16);
}

#define GLL16(src, dst) __builtin_amdgcn_global_load_lds( \
    (const __attribute__((address_space(1))) unsigned int*)(src), \
    (__attribute__((address_space(3))) unsigned int*)(dst), 16, 0, 0)

// ---------------- fused setup: bucketed CSR count + weight pack + xenc ----------------
#define XB (TT * NN / 4)

__global__ __launch_bounds__(256) void k_setup(
    const float* __restrict__ na, const float* __restrict__ W_ne,
    const float* __restrict__ b_ne, unsigned short* __restrict__ xenc,
    const int* __restrict__ r, const int* __restrict__ s,
    const int* __restrict__ Li, int* cnt_r, int* cnt_s, int* cnt_L,
    const float* __restrict__ W_eb, const float* __restrict__ W_nb,
    const float* __restrict__ W_d1, const float* __restrict__ W_i1,
    const float* __restrict__ emb, unsigned short* __restrict__ Bpe,
    unsigned short* __restrict__ Bpu, unsigned short* __restrict__ Bpn,
    unsigned short* __restrict__ Bpd, unsigned short* __restrict__ emb_bf) {
    int bid = blockIdx.x;
    if (bid < CNTB) {
        const int bucket = bid & 7;
        const int nlo = bucket * NBKT;
        const int cid = bid >> 3;
        const int stride = (CNTB >> 3) * 256;
        for (int i = cid * 256 + threadIdx.x; i < EE; i += stride) {
            int rv = r[i];
            if ((unsigned)(rv - nlo) < (unsigned)NBKT) atomicAdd(&cnt_r[rv], 1);
            int sv = s[i];
            if ((unsigned)(sv - nlo) < (unsigned)NBKT) atomicAdd(&cnt_s[sv], 1);
        }
        for (int i = cid * 256 + threadIdx.x; i < NZ; i += stride) {
            int lv = Li[i];
            if ((unsigned)(lv - nlo) < (unsigned)NBKT) atomicAdd(&cnt_L[lv], 1);
        }
        return;
    }
    bid -= CNTB;
    if (bid < 96) {
        int t = bid * 256 + threadIdx.x;
        if (t < 2 * 8 * 512) {
            int i = t & 7, l = (t >> 3) & 63, kb = (t >> 9) & 7, ch = t >> 12;
            int colv = ch * 32 + (l & 31);
            int k = kb * 16 + (l >> 5) * 8 + i;
            Bpe[t] = f2bf(W_eb[k * 64 + colv]);
        }
        if (t < 4 * 8 * 512) {
            int i = t & 7, l = (t >> 3) & 63, kb = (t >> 9) & 7, g = t >> 12;
            int colv = (g & 1) * 32 + (l & 31);
            int k = 128 + (g >> 1) * 128 + kb * 16 + (l >> 5) * 8 + i;
            Bpu[t] = f2bf(W_eb[k * 64 + colv]);
        }
        if (t < 2 * 16 * 512) {
            int i = t & 7, l = (t >> 3) & 63, kb = (t >> 9) % 16, ch = t / (16 * 512);
            int colv = ch * 32 + (l & 31);
            int k = kb * 16 + (l >> 5) * 8 + i;
            Bpn[t] = f2bf(W_nb[k * 64 + colv]);
        }
        if (t < 4 * 4 * 512) {
            int i = t & 7, l = (t >> 3) & 63, kb = (t >> 9) & 3, sec = t >> 11;
            int colv = (sec & 1) * 32 + (l & 31);
            int k = kb * 16 + (l >> 5) * 8 + i;
            const float* W = (sec < 2) ? W_d1 : W_i1;
            Bpd[t] = f2bf(W[k * 64 + colv]);
        }
        if (t < 100 * 64) emb_bf[t] = f2bf(emb[t]);
        return;
    }
    bid -= 96;
    int row = bid * 4 + (threadIdx.x >> 6);
    int j = threadIdx.x & 63;
    float4 a = *(const float4*)&na[(size_t)row * 4];
    float v = b_ne[j] + a.x * W_ne[j] + a.y * W_ne[64 + j] + a.z * W_ne[128 + j] + a.w * W_ne[192 + j];
    xenc[(size_t)row * 64 + j] = f2bf(fmaxf(v, 0.f));
}

__global__ __launch_bounds__(1024) void k_scan(int* cnt, int* rowp, int* wp) {
    int which = blockIdx.x;
    int* c = cnt + which * NN;
    int* row = rowp + which * (NN + 1);
    int* w = wp + which * NN;
    __shared__ int ssum[1024];
    int tid = threadIdx.x;
    const int CH = (NN + 1023) / 1024;
    int base = tid * CH;
    int s = 0;
    for (int i = 0; i < CH; ++i) { int idx = base + i; s += (idx < NN) ? c[idx] : 0; }
    ssum[tid] = s;
    __syncthreads();
    for (int o = 1; o < 1024; o <<= 1) {
        int v = (tid >= o) ? ssum[tid - o] : 0;
        __syncthreads();
        ssum[tid] += v;
        __syncthreads();
    }
    int run = (tid > 0) ? ssum[tid - 1] : 0;
    for (int i = 0; i < CH; ++i) {
        int idx = base + i;
        if (idx < NN) { row[idx] = run; w[idx] = run; run += c[idx]; }
    }
    if (tid == 1023) row[NN] = ssum[1023];
}

// ---------------- gbias-only kernel (t>=1) ----------------
__global__ __launch_bounds__(64) void k_gbias(
    const float* __restrict__ W_gb, const float* __restrict__ b_gb,
    const float* __restrict__ W_eb, const float* __restrict__ b_eb,
    const float* __restrict__ W_nb, const float* __restrict__ b_nb,
    float* __restrict__ g_cur, float* __restrict__ e_sum, float* __restrict__ x_sum,
    float* __restrict__ gb_eb, float* __restrict__ gb_nb) {
    int j = threadIdx.x;
    float a = b_gb[j];
    for (int k = 0; k < 64; ++k) a += (e_sum[k] / (float)EE) * W_gb[k * 64 + j];
    for (int k = 0; k < 64; ++k) a += (x_sum[k] / (float)NN) * W_gb[(64 + k) * 64 + j];
    for (int k = 0; k < 64; ++k) a += g_cur[k] * W_gb[(128 + k) * 64 + j];
    float gv = fmaxf(a, 0.f);
    g_cur[j] = gv;
    e_sum[j] = 0.f;
    x_sum[j] = 0.f;
    float a1 = b_eb[j], a2 = b_nb[j];
    for (int k = 0; k < 64; ++k) {
        float gk = __shfl(gv, k, 64);
        a1 = fmaf(gk, W_eb[(384 + k) * 64 + j], a1);
        a2 = fmaf(gk, W_nb[(256 + k) * 64 + j], a2);
    }
    gb_eb[j] = a1;
    gb_nb[j] = a2;
}

// ------- fused: XCD-bucketed scatter (builds permuted arrays) + usr(t=0) -------
// Permutation: position p (recv-CSR order) holds edge i=inverse; we store
//   rpos[i]=p, sp[p]=s[i], rp[p]=r[i], ap[t][p]=edge_attr[t][i].
__global__ __launch_bounds__(256) void k_susr(
    int scatterb, int nusr,
    const int* __restrict__ sidx, const int* __restrict__ ridx,
    const int* __restrict__ Li, const int* __restrict__ Lj,
    const float* __restrict__ Lv, const int* __restrict__ edge_attr,
    int* wp_r, int* wp_s, int* wp_L,
    int* __restrict__ rpos, int* __restrict__ sp, int* __restrict__ rp,
    int* __restrict__ ap, int* __restrict__ col_s, uint2* __restrict__ col_L8,
    const unsigned short* __restrict__ xenc0, const unsigned short* __restrict__ hx_bf,
    const unsigned short* __restrict__ Bpu, unsigned int* __restrict__ usr,
    const float* __restrict__ W_eb, const float* __restrict__ b_eb,
    const float* __restrict__ W_nb, const float* __restrict__ b_nb,
    float* __restrict__ g_cur, float* __restrict__ gb_eb, float* __restrict__ gb_nb) {
    const int tid = threadIdx.x;
    if ((int)blockIdx.x < scatterb) {
        const int bucket = blockIdx.x & 7;
        const int nlo = bucket * NBKT;
        const int cid = blockIdx.x >> 3;
        const int stride = (scatterb >> 3) * 256;
        for (int i = cid * 256 + tid; i < EE; i += stride) {
            int rv = ridx[i];
            int sv = sidx[i];
            if ((unsigned)(rv - nlo) < (unsigned)NBKT) {
                int pos = atomicAdd(&wp_r[rv], 1);
                rpos[i] = pos;
                sp[pos] = sv;
                rp[pos] = rv;
                ap[pos] = edge_attr[i];
                ap[EE + pos] = edge_attr[EE + i];
                ap[2 * EE + pos] = edge_attr[2 * EE + i];
                ap[3 * EE + pos] = edge_attr[3 * EE + i];
            }
            if ((unsigned)(sv - nlo) < (unsigned)NBKT)
                col_s[atomicAdd(&wp_s[sv], 1)] = i;
        }
        for (int i = cid * 256 + tid; i < NZ; i += stride) {
            int lv = Li[i];
            if ((unsigned)(lv - nlo) < (unsigned)NBKT) {
                int pos = atomicAdd(&wp_L[lv], 1);
                uint2 v;
                v.x = (unsigned int)Lj[i];
                v.y = __float_as_uint(Lv[i]);
                col_L8[pos] = v;
            }
        }
        return;
    }
    // usr(t=0): 4 waves per block, one 32-node group per wave
    const int ln = tid & 63;
    const int wid = ((int)blockIdx.x - scatterb) * 4 + (tid >> 6);
    const int er = ln & 31, hi = ln >> 5;

    if (wid == 0) {
        int j = ln;
        float gv = g_cur[j];
        float a1 = b_eb[j], a2 = b_nb[j];
        for (int k = 0; k < 64; ++k) {
            float gk = __shfl(gv, k, 64);
            a1 = fmaf(gk, W_eb[(384 + k) * 64 + j], a1);
            a2 = fmaf(gk, W_nb[(256 + k) * 64 + j], a2);
        }
        gb_eb[j] = a1;
        gb_nb[j] = a2;
    }
    if (wid >= nusr) return;

    const int n0 = wid * 32;
    const int n = n0 + er;

    f32x16 a0, a1, a2, a3;
    #pragma unroll
    for (int i = 0; i < 16; ++i) { a0[i] = 0.f; a1[i] = 0.f; a2[i] = 0.f; a3[i] = 0.f; }

    const unsigned short* sx = xenc0 + (size_t)64 * n + hi * 8;
    const unsigned short* sh = hx_bf + (size_t)64 * n + hi * 8;
    #pragma unroll
    for (int c = 0; c < 2; ++c) {
        const unsigned short* src = c ? sh : sx;
        #pragma unroll
        for (int kb = 0; kb < 4; ++kb) {
            bf16x8 a = *(const bf16x8*)(src + kb * 16);
            int kg = c * 4 + kb;
            bf16x8 b0 = *(const bf16x8*)&Bpu[(size_t)((0 * 8 + kg) * 64 + ln) * 8];
            bf16x8 b1 = *(const bf16x8*)&Bpu[(size_t)((1 * 8 + kg) * 64 + ln) * 8];
            bf16x8 b2 = *(const bf16x8*)&Bpu[(size_t)((2 * 8 + kg) * 64 + ln) * 8];
            bf16x8 b3 = *(const bf16x8*)&Bpu[(size_t)((3 * 8 + kg) * 64 + ln) * 8];
            a0 = __builtin_amdgcn_mfma_f32_32x32x16_bf16(a, b0, a0, 0, 0, 0);
            a1 = __builtin_amdgcn_mfma_f32_32x32x16_bf16(a, b1, a1, 0, 0, 0);
            a2 = __builtin_amdgcn_mfma_f32_32x32x16_bf16(a, b2, a2, 0, 0, 0);
            a3 = __builtin_amdgcn_mfma_f32_32x32x16_bf16(a, b3, a3, 0, 0, 0);
        }
    }
    #pragma unroll
    for (int r = 0; r < 16; ++r) {
        int row = (r & 3) + 8 * (r >> 2) + 4 * hi;
        size_t o = (size_t)(n0 + row) * 64;
        usr[o + er]      = (unsigned int)f2bf(a0[r]) | ((unsigned int)f2bf(a1[r]) << 16);
        usr[o + 32 + er] = (unsigned int)f2bf(a2[r]) | ((unsigned int)f2bf(a3[r]) << 16);
    }
}

// ----- edge block over positions (recv-sorted); fix blocks build col_s2r at t=0 -----
__global__ __launch_bounds__(512) void k_edge(
    int first, int fixb, unsigned short* __restrict__ h_e,
    const unsigned short* __restrict__ emb_bf,
    const unsigned int* __restrict__ usr, const int* __restrict__ ap_t,
    const int* __restrict__ sp, const int* __restrict__ rp,
    const unsigned short* __restrict__ Bp, const float* __restrict__ gbias,
    float* __restrict__ e_sum,
    const int* __restrict__ col_s, const int* __restrict__ rpos,
    int* __restrict__ col_s2r) {
    __shared__ unsigned short sBe[8192];
    __shared__ float sRed[8][64];
    const int tid = threadIdx.x;

    if ((int)blockIdx.x < fixb) {
        int p = blockIdx.x * 512 + tid;  // fixb = EE/512
        col_s2r[p] = rpos[col_s[p]];
        return;
    }

    const int w = tid >> 6, ln = tid & 63;
    const int er = ln & 31, hi = ln >> 5;
    const int ebase = ((int)blockIdx.x - fixb) * 256 + w * 32;
    const int e = ebase + er;

    const int siv = sp[e];
    const int riv = rp[e];
    const int ai = ap_t[e];

    #pragma unroll
    for (int i = 0; i < 2; ++i) {
        int off = i * 4096 + w * 512;
        GLL16(Bp + off + ln * 8, sBe + off);
    }

    const unsigned short* s0 = emb_bf + (size_t)64 * ai + hi * 8;
    const unsigned short* s1 = h_e + (size_t)64 * e + hi * 8;
    bf16x8 a0 = *(const bf16x8*)(s0);
    bf16x8 a1 = *(const bf16x8*)(s0 + 16);
    bf16x8 a2 = *(const bf16x8*)(s0 + 32);
    bf16x8 a3 = *(const bf16x8*)(s0 + 48);
    bf16x8 a4{}, a5{}, a6{}, a7{};
    if (!first) {
        a4 = *(const bf16x8*)(s1);
        a5 = *(const bf16x8*)(s1 + 16);
        a6 = *(const bf16x8*)(s1 + 32);
        a7 = *(const bf16x8*)(s1 + 48);
    }

    f32x16 acc0, acc1;
    #pragma unroll
    for (int i = 0; i < 16; ++i) { acc0[i] = 0.f; acc1[i] = 0.f; }

    __syncthreads();

    #define EMM(AF, KG)                                                              \
        {                                                                            \
            bf16x8 b0 = *(const bf16x8*)&sBe[(((KG)) * 64 + ln) * 8];                \
            bf16x8 b1 = *(const bf16x8*)&sBe[((8 + (KG)) * 64 + ln) * 8];            \
            acc0 = __builtin_amdgcn_mfma_f32_32x32x16_bf16(AF, b0, acc0, 0, 0, 0);   \
            acc1 = __builtin_amdgcn_mfma_f32_32x32x16_bf16(AF, b1, acc1, 0, 0, 0);   \
        }
    EMM(a0, 0) EMM(a1, 1) EMM(a2, 2) EMM(a3, 3)
    if (!first) {
        EMM(a4, 4) EMM(a5, 5) EMM(a6, 6) EMM(a7, 7)
    }
    #undef EMM

    const float gb0 = gbias[er], gb1 = gbias[er + 32];
    float cs0 = 0.f, cs1 = 0.f;
    #pragma unroll
    for (int r = 0; r < 16; ++r) {
        int row = (r & 3) + 8 * (r >> 2) + 4 * hi;
        int si_row = __shfl(siv, row, 64);
        int ri_row = __shfl(riv, row, 64);
        unsigned int us = usr[(size_t)si_row * 64 + er];
        unsigned int ur = usr[(size_t)ri_row * 64 + 32 + er];
        size_t o = (size_t)(ebase + row) * 64;
        float v0 = fmaxf(acc0[r] + bf2f((unsigned short)(us & 0xFFFF))
                                 + bf2f((unsigned short)(ur & 0xFFFF)) + gb0, 0.f);
        float v1 = fmaxf(acc1[r] + bf2f((unsigned short)(us >> 16))
                                 + bf2f((unsigned short)(ur >> 16)) + gb1, 0.f);
        cs0 += v0; cs1 += v1;
        h_e[o + er] = f2bf(v0);
        h_e[o + er + 32] = f2bf(v1);
    }
    cs0 += __shfl_xor(cs0, 32, 64);
    cs1 += __shfl_xor(cs1, 32, 64);
    if (hi == 0) { sRed[w][er] = cs0; sRed[w][er + 32] = cs1; }
    __syncthreads();
    if (w == 0) {
        float t = 0.f;
        #pragma unroll
        for (int q = 0; q < 8; ++q) t += sRed[q][ln];
        atomicAdd(&e_sum[ln], t);
    }
}

// ------- fused gather(t) [sequential recv, mapped sent] + lap(t-1) -------
__global__ __launch_bounds__(256) void k_glap(
    int gatherb,
    const unsigned short* __restrict__ h_e, const int* __restrict__ row_r,
    const int* __restrict__ row_s, const int* __restrict__ col_s2r,
    unsigned short* __restrict__ recv, unsigned short* __restrict__ sentb,
    const unsigned short* __restrict__ hx_bf, const int* __restrict__ row_L,
    const uint2* __restrict__ col_L8, const float* __restrict__ coeff,
    float* __restrict__ spat_prev) {
    if ((int)blockIdx.x < gatherb) {
        int t = blockIdx.x * 256 + threadIdx.x;
        int sub = t & 63, n = t >> 6;
        int g = sub & 15, which = (sub >> 4) & 1, half = sub >> 5;
        const int* rowp = which ? row_s : row_r;
        unsigned short* outp = which ? sentb : recv;

        float a0 = 0.f, a1 = 0.f, a2 = 0.f, a3 = 0.f;
        int b0 = rowp[n], b1 = rowp[n + 1];
        int mid = b0 + ((b1 - b0) >> 1);
        int p0 = half ? mid : b0;
        int p1 = half ? b1 : mid;
        if (which == 0) {
            // recv: h_e rows are contiguous in position order
            for (int p = p0; p < p1; ++p) {
                uint2 v = *(const uint2*)&h_e[(size_t)64 * p + g * 4];
                a0 += bf2f((unsigned short)(v.x & 0xFFFF));
                a1 += bf2f((unsigned short)(v.x >> 16));
                a2 += bf2f((unsigned short)(v.y & 0xFFFF));
                a3 += bf2f((unsigned short)(v.y >> 16));
            }
        } else {
            for (int p = p0; p < p1; ++p) {
                int r2 = col_s2r[p];
                uint2 v = *(const uint2*)&h_e[(size_t)64 * r2 + g * 4];
                a0 += bf2f((unsigned short)(v.x & 0xFFFF));
                a1 += bf2f((unsigned short)(v.x >> 16));
                a2 += bf2f((unsigned short)(v.y & 0xFFFF));
                a3 += bf2f((unsigned short)(v.y >> 16));
            }
        }
        a0 += __shfl_xor(a0, 32, 64);
        a1 += __shfl_xor(a1, 32, 64);
        a2 += __shfl_xor(a2, 32, 64);
        a3 += __shfl_xor(a3, 32, 64);
        if (half == 0) {
            uint2 packed;
            packed.x = (unsigned int)f2bf(a0) | ((unsigned int)f2bf(a1) << 16);
            packed.y = (unsigned int)f2bf(a2) | ((unsigned int)f2bf(a3) << 16);
            *(uint2*)&outp[(size_t)64 * n + g * 4] = packed;
        }
        return;
    }
    int t = ((int)blockIdx.x - gatherb) * 256 + threadIdx.x;
    int sub = t & 31, n = t >> 5;
    int g = sub & 15, half = sub >> 4;
    float a0 = 0.f, a1 = 0.f, a2 = 0.f, a3 = 0.f;
    int b0 = row_L[n], b1 = row_L[n + 1];
    int mid = b0 + ((b1 - b0) >> 1);
    int p0 = half ? mid : b0;
    int p1 = half ? b1 : mid;
    for (int p = p0; p < p1; ++p) {
        uint2 e = col_L8[p];
        float lv = __uint_as_float(e.y);
        uint2 hv = *(const uint2*)&hx_bf[(size_t)64 * e.x + g * 4];
        a0 = fmaf(lv, bf2f((unsigned short)(hv.x & 0xFFFF)), a0);
        a1 = fmaf(lv, bf2f((unsigned short)(hv.x >> 16)), a1);
        a2 = fmaf(lv, bf2f((unsigned short)(hv.y & 0xFFFF)), a2);
        a3 = fmaf(lv, bf2f((unsigned short)(hv.y >> 16)), a3);
    }
    a0 += __shfl_xor(a0, 16, 64);
    a1 += __shfl_xor(a1, 16, 64);
    a2 += __shfl_xor(a2, 16, 64);
    a3 += __shfl_xor(a3, 16, 64);
    if (half == 0) {
        float c = coeff[0];
        float4 outv = {c * a0, c * a1, c * a2, c * a3};
        *(float4*)&spat_prev[(size_t)64 * n + g * 4] = outv;
    }
}

// ---------------- node block + fused usr(t+1) via swizzled LDS hx tile ----------------
#define NODE_CHUNK(CIDX, BASE)                                                          \
    {                                                                                   \
        const unsigned short* src = (BASE) + hi * 8;                                    \
        _Pragma("unroll") for (int kb = 0; kb < 4; ++kb) {                              \
            bf16x8 a = *(const bf16x8*)(src + kb * 16);                                 \
            bf16x8 b0 = *(const bf16x8*)&Bp[(size_t)(((CIDX)*4 + kb) * 64 + ln) * 8];   \
            bf16x8 b1 = *(const bf16x8*)&Bp[(size_t)((16 + (CIDX)*4 + kb) * 64 + ln) * 8]; \
            acc0 = __builtin_amdgcn_mfma_f32_32x32x16_bf16(a, b0, acc0, 0, 0, 0);       \
            acc1 = __builtin_amdgcn_mfma_f32_32x32x16_bf16(a, b1, acc1, 0, 0, 0);       \
        }                                                                               \
    }

__global__ __launch_bounds__(64) void k_node(
    int has_next,
    const unsigned short* __restrict__ recv, const unsigned short* __restrict__ sentb,
    const unsigned short* __restrict__ xenc_t, float* __restrict__ h_x,
    unsigned short* __restrict__ hx_bf, const unsigned short* __restrict__ Bp,
    const float* __restrict__ gbias, float* __restrict__ x_sum,
    unsigned short* __restrict__ hid_t, float* __restrict__ timed_t,
    const unsigned short* __restrict__ xenc_next,
    const unsigned short* __restrict__ Bpu, unsigned int* __restrict__ usr) {
    __shared__ unsigned short sHx[32 * 64];
    const int ln = threadIdx.x;
    const int er = ln & 31, hi = ln >> 5;
    const int n0 = blockIdx.x * 32;
    const int n = n0 + er;

    f32x16 acc0, acc1;
    #pragma unroll
    for (int i = 0; i < 16; ++i) { acc0[i] = 0.f; acc1[i] = 0.f; }

    NODE_CHUNK(0, recv + (size_t)64 * n)
    NODE_CHUNK(1, sentb + (size_t)64 * n)
    NODE_CHUNK(2, xenc_t + (size_t)64 * n)
    NODE_CHUNK(3, hx_bf + (size_t)64 * n)

    const float gb0 = gbias[er], gb1 = gbias[er + 32];
    const int g0 = er >> 3, w0 = er & 7;
    float cs0 = 0.f, cs1 = 0.f;
    #pragma unroll
    for (int r = 0; r < 16; ++r) {
        int row = (r & 3) + 8 * (r >> 2) + 4 * hi;
        size_t o = (size_t)(n0 + row) * 64;
        float x0 = fmaxf(acc0[r] + gb0, 0.f);
        float x1 = fmaxf(acc1[r] + gb1, 0.f);
        cs0 += x0; cs1 += x1;
        float hx0 = h_x[o + er] + x0;
        float hx1 = h_x[o + er + 32] + x1;
        unsigned short hb0 = f2bf(hx0), hb1 = f2bf(hx1);
        h_x[o + er] = hx0;        h_x[o + er + 32] = hx1;
        hx_bf[o + er] = hb0;      hx_bf[o + er + 32] = hb1;
        hid_t[o + er] = hb0;      hid_t[o + er + 32] = hb1;
        timed_t[o + er] = x0;     timed_t[o + er + 32] = x1;
        int rs = row & 7;
        sHx[row * 64 + (((g0 ^ rs) << 3) | w0)] = hb0;
        sHx[row * 64 + ((((g0 + 4) ^ rs) << 3) | w0)] = hb1;
    }
    cs0 += __shfl_xor(cs0, 32, 64);
    cs1 += __shfl_xor(cs1, 32, 64);
    if (hi == 0) {
        atomicAdd(&x_sum[er], cs0);
        atomicAdd(&x_sum[er + 32], cs1);
    }
    if (!has_next) return;

    __syncthreads();

    f32x16 a0, a1, a2, a3;
    #pragma unroll
    for (int i = 0; i < 16; ++i) { a0[i] = 0.f; a1[i] = 0.f; a2[i] = 0.f; a3[i] = 0.f; }

    const unsigned short* sx = xenc_next + (size_t)64 * n + hi * 8;
    #pragma unroll
    for (int c = 0; c < 2; ++c) {
        #pragma unroll
        for (int kb = 0; kb < 4; ++kb) {
            bf16x8 a;
            if (c == 0) {
                a = *(const bf16x8*)(sx + kb * 16);
            } else {
                int gi = hi + 2 * kb;
                a = *(const bf16x8*)&sHx[er * 64 + ((gi ^ (er & 7)) << 3)];
            }
            int kg = c * 4 + kb;
            bf16x8 b0 = *(const bf16x8*)&Bpu[(size_t)((0 * 8 + kg) * 64 + ln) * 8];
            bf16x8 b1 = *(const bf16x8*)&Bpu[(size_t)((1 * 8 + kg) * 64 + ln) * 8];
            bf16x8 b2 = *(const bf16x8*)&Bpu[(size_t)((2 * 8 + kg) * 64 + ln) * 8];
            bf16x8 b3 = *(const bf16x8*)&Bpu[(size_t)((3 * 8 + kg) * 64 + ln) * 8];
            a0 = __builtin_amdgcn_mfma_f32_32x32x16_bf16(a, b0, a0, 0, 0, 0);
            a1 = __builtin_amdgcn_mfma_f32_32x32x16_bf16(a, b1, a1, 0, 0, 0);
            a2 = __builtin_amdgcn_mfma_f32_32x32x16_bf16(a, b2, a2, 0, 0, 0);
            a3 = __builtin_amdgcn_mfma_f32_32x32x16_bf16(a, b3, a3, 0, 0, 0);
        }
    }
    #pragma unroll
    for (int r = 0; r < 16; ++r) {
        int row = (r & 3) + 8 * (r >> 2) + 4 * hi;
        size_t o = (size_t)(n0 + row) * 64;
        usr[o + er]      = (unsigned int)f2bf(a0[r]) | ((unsigned int)f2bf(a1[r]) << 16);
        usr[o + 32 + er] = (unsigned int)f2bf(a2[r]) | ((unsigned int)f2bf(a3[r]) << 16);
    }
}

// ---------------- decoders: MFMA layer1, LDS transpose, scalar layer2 ----------------
__global__ __launch_bounds__(256) void k_dec(
    const unsigned short* __restrict__ hid_bf, const unsigned short* __restrict__ Bpd,
    const float* __restrict__ b_d1, const float* __restrict__ W_d2,
    const float* __restrict__ b_d2, const float* __restrict__ b_i1,
    const float* __restrict__ W_i2, const float* __restrict__ b_i2,
    float* __restrict__ out_nodes, float* __restrict__ pred_in) {
    __shared__ unsigned short sDec[4][32 * 138];
    const int tid = threadIdx.x;
    const int w = tid >> 6, ln = tid & 63;
    const int er = ln & 31, hi = ln >> 5;
    const int row0 = (blockIdx.x * 4 + w) * 32;

    f32x16 ad0, ad1, ai0, ai1;
    #pragma unroll
    for (int i = 0; i < 16; ++i) { ad0[i] = 0.f; ad1[i] = 0.f; ai0[i] = 0.f; ai1[i] = 0.f; }

    const unsigned short* src = hid_bf + (size_t)(row0 + er) * 64 + hi * 8;
    #pragma unroll
    for (int kb = 0; kb < 4; ++kb) {
        bf16x8 a = *(const bf16x8*)(src + kb * 16);
        bf16x8 bd0 = *(const bf16x8*)&Bpd[((0 * 4 + kb) * 64 + ln) * 8];
        bf16x8 bd1 = *(const bf16x8*)&Bpd[((4 + kb) * 64 + ln) * 8];
        bf16x8 bi0 = *(const bf16x8*)&Bpd[((8 + kb) * 64 + ln) * 8];
        bf16x8 bi1 = *(const bf16x8*)&Bpd[((12 + kb) * 64 + ln) * 8];
        ad0 = __builtin_amdgcn_mfma_f32_32x32x16_bf16(a, bd0, ad0, 0, 0, 0);
        ad1 = __builtin_amdgcn_mfma_f32_32x32x16_bf16(a, bd1, ad1, 0, 0, 0);
        ai0 = __builtin_amdgcn_mfma_f32_32x32x16_bf16(a, bi0, ai0, 0, 0, 0);
        ai1 = __builtin_amdgcn_mfma_f32_32x32x16_bf16(a, bi1, ai1, 0, 0, 0);
    }

    const float bd0v = b_d1[er], bd1v = b_d1[er + 32];
    const float bi0v = b_i1[er], bi1v = b_i1[er + 32];
    unsigned short* sw = &sDec[w][0];
    #pragma unroll
    for (int r = 0; r < 16; ++r) {
        int row = (r & 3) + 8 * (r >> 2) + 4 * hi;
        sw[row * 138 + er]       = f2bf(fmaxf(ad0[r] + bd0v, 0.f));
        sw[row * 138 + er + 32]  = f2bf(fmaxf(ad1[r] + bd1v, 0.f));
        sw[row * 138 + er + 64]  = f2bf(fmaxf(ai0[r] + bi0v, 0.f));
        sw[row * 138 + er + 96]  = f2bf(fmaxf(ai1[r] + bi1v, 0.f));
    }
    __syncthreads();

    const int g_row = row0 + er;
    if (hi == 0) {
        float s = 0.f;
        for (int k = 0; k < 32; ++k) {
            unsigned int u = *(const unsigned int*)&sw[er * 138 + 2 * k];
            s = fmaf(bf2f((unsigned short)(u & 0xFFFF)), W_d2[2 * k], s);
            s = fmaf(bf2f((unsigned short)(u >> 16)), W_d2[2 * k + 1], s);
        }
        out_nodes[g_row] = s + b_d2[0];
    } else {
        float s0 = 0.f, s1 = 0.f, s2 = 0.f, s3 = 0.f;
        for (int k = 0; k < 32; ++k) {
            unsigned int u = *(const unsigned int*)&sw[er * 138 + 64 + 2 * k];
            float vlo = bf2f((unsigned short)(u & 0xFFFF));
            float vhi = bf2f((unsigned short)(u >> 16));
            float4 w0 = *(const float4*)&W_i2[(2 * k) * 4];
            float4 w1 = *(const float4*)&W_i2[(2 * k + 1) * 4];
            s0 = fmaf(vlo, w0.x, fmaf(vhi, w1.x, s0));
            s1 = fmaf(vlo, w0.y, fmaf(vhi, w1.y, s1));
            s2 = fmaf(vlo, w0.z, fmaf(vhi, w1.z, s2));
            s3 = fmaf(vlo, w0.w, fmaf(vhi, w1.w, s3));
        }
        float4 pv = {s0 + b_i2[0], s1 + b_i2[1], s2 + b_i2[2], s3 + b_i2[3]};
        *(float4*)&pred_in[(size_t)4 * g_row] = pv;
    }
}

extern "C" void kernel_launch(void* const* d_in, const int* in_sizes, int n_in,
                              void* d_out, int out_size, void* d_ws, size_t ws_size,
                              hipStream_t stream) {
    (void)in_sizes; (void)n_in; (void)out_size; (void)ws_size;
    const float* node_attr   = (const float*)d_in[0];
    const float* global_attr = (const float*)d_in[1];
    const float* L_values    = (const float*)d_in[2];
    const float* coeff       = (const float*)d_in[3];
    const int*   edge_attr   = (const int*)d_in[4];
    const int*   edge_index  = (const int*)d_in[5];
    const int*   L_index     = (const int*)d_in[6];
    const float* emb  = (const float*)d_in[8];
    const float* W_ne = (const float*)d_in[9];
    const float* b_ne = (const float*)d_in[10];
    const float* W_eb = (const float*)d_in[11];
    const float* b_eb = (const float*)d_in[12];
    const float* W_nb = (const float*)d_in[13];
    const float* b_nb = (const float*)d_in[14];
    const float* W_gb = (const float*)d_in[15];
    const float* b_gb = (const float*)d_in[16];
    const float* W_d1 = (const float*)d_in[17];
    const float* b_d1 = (const float*)d_in[18];
    const float* W_d2 = (const float*)d_in[19];
    const float* b_d2 = (const float*)d_in[20];
    const float* W_i1 = (const float*)d_in[21];
    const float* b_i1 = (const float*)d_in[22];
    const float* W_i2 = (const float*)d_in[23];
    const float* b_i2 = (const float*)d_in[24];

    const int* s_idx = edge_index;
    const int* r_idx = edge_index + EE;
    const int* Li = L_index;
    const int* Lj = L_index + NZ;

    char* ws = (char*)d_ws;
    size_t off = 0;
    auto alloc = [&](size_t bytes) -> void* {
        void* p = ws + off;
        off = (off + bytes + 255) & ~(size_t)255;
        return p;
    };
    unsigned short* xenc   = (unsigned short*)alloc((size_t)TT * NN * 64 * 2);
    unsigned short* hid    = (unsigned short*)alloc((size_t)TT * NN * 64 * 2);
    float*          h_x    = (float*)alloc((size_t)NN * 64 * 4);
    unsigned short* hx_bf  = (unsigned short*)alloc((size_t)NN * 64 * 2);
    unsigned short* h_e    = (unsigned short*)alloc((size_t)EE * 64 * 2);
    unsigned short* recv   = (unsigned short*)alloc((size_t)NN * 64 * 2);
    unsigned short* sentb  = (unsigned short*)alloc((size_t)NN * 64 * 2);
    unsigned int*   usr    = (unsigned int*)alloc((size_t)NN * 64 * 4);
    float* smalls          = (float*)alloc(2048);
    unsigned short* Bpe    = (unsigned short*)alloc((size_t)2 * 8 * 512 * 2);
    unsigned short* Bpu    = (unsigned short*)alloc((size_t)4 * 8 * 512 * 2);
    unsigned short* Bpn    = (unsigned short*)alloc((size_t)2 * 16 * 512 * 2);
    unsigned short* Bpd    = (unsigned short*)alloc((size_t)4 * 4 * 512 * 2);
    unsigned short* emb_bf = (unsigned short*)alloc((size_t)100 * 64 * 2);
    int* cnt     = (int*)alloc((size_t)3 * NN * 4);
    int* rowp    = (int*)alloc((size_t)3 * (NN + 1) * 4);
    int* wp      = (int*)alloc((size_t)3 * NN * 4);
    int* col_s   = (int*)alloc((size_t)EE * 4);
    int* rpos    = (int*)alloc((size_t)EE * 4);
    int* sp      = (int*)alloc((size_t)EE * 4);
    int* rp      = (int*)alloc((size_t)EE * 4);
    int* ap      = (int*)alloc((size_t)4 * EE * 4);
    int* col_s2r = (int*)alloc((size_t)EE * 4);
    uint2* col_L8 = (uint2*)alloc((size_t)NZ * 8);

    float* g_cur = smalls;
    float* e_sum = smalls + 64;
    float* x_sum = smalls + 128;
    float* gb_eb = smalls + 192;
    float* gb_nb = smalls + 256;
    int* cnt_r = cnt, *cnt_s = cnt + NN, *cnt_L = cnt + 2 * NN;
    int* row_r = rowp, *row_s = rowp + (NN + 1), *row_L = rowp + 2 * (NN + 1);
    int* wp_r = wp, *wp_s = wp + NN, *wp_L = wp + 2 * NN;

    float* out_nodes = (float*)d_out;                    // [T,N,1]
    float* time_d = out_nodes + (size_t)TT * NN;         // [T,N,64]
    float* spat_d = time_d + (size_t)TT * NN * 64;       // [T,N,64]
    float* pred_in = spat_d + (size_t)TT * NN * 64;      // [T,N,4]

    hipMemsetAsync(h_x, 0, (size_t)NN * 64 * 4, stream);
    hipMemsetAsync(hx_bf, 0, (size_t)NN * 64 * 2, stream);
    hipMemsetAsync(smalls, 0, 2048, stream);
    hipMemsetAsync(cnt, 0, (size_t)3 * NN * 4, stream);
    hipMemcpyAsync(g_cur, global_attr, 64 * 4, hipMemcpyDeviceToDevice, stream);

    k_setup<<<CNTB + 96 + XB, 256, 0, stream>>>(node_attr, W_ne, b_ne, xenc,
                                                r_idx, s_idx, Li, cnt_r, cnt_s, cnt_L,
                                                W_eb, W_nb, W_d1, W_i1, emb,
                                                Bpe, Bpu, Bpn, Bpd, emb_bf);
    k_scan<<<3, 1024, 0, stream>>>(cnt, rowp, wp);
    const int NUSR = NN / 32;               // 625
    const int USRB = (NUSR + 3) / 4;        // 157
    k_susr<<<SCB + USRB, 256, 0, stream>>>(SCB, NUSR,
                                           s_idx, r_idx, Li, Lj, L_values, edge_attr,
                                           wp_r, wp_s, wp_L,
                                           rpos, sp, rp, ap, col_s, col_L8,
                                           xenc, hx_bf, Bpu, usr,
                                           W_eb, b_eb, W_nb, b_nb,
                                           g_cur, gb_eb, gb_nb);

    const int GBg = NN * 64 / 256;  // 5000 gather blocks
    const int GBl = NN * 32 / 256;  // 2500 lap blocks
    for (int t = 0; t < TT; ++t) {
        const unsigned short* xenc_t = xenc + (size_t)t * NN * 64;
        if (t > 0)
            k_gbias<<<1, 64, 0, stream>>>(W_gb, b_gb, W_eb, b_eb, W_nb, b_nb,
                                          g_cur, e_sum, x_sum, gb_eb, gb_nb);
        int fixb = (t == 0) ? EE / 512 : 0;
        k_edge<<<fixb + EE / 256, 512, 0, stream>>>(
            t == 0, fixb, h_e, emb_bf, usr, ap + (size_t)t * EE, sp, rp,
            Bpe, gb_eb, e_sum, col_s, rpos, col_s2r);
        int grid = GBg + ((t > 0) ? GBl : 0);
        float* spat_prev = spat_d + (size_t)((t > 0) ? t - 1 : 0) * NN * 64;
        k_glap<<<grid, 256, 0, stream>>>(GBg, h_e, row_r, row_s, col_s2r,
                                         recv, sentb, hx_bf, row_L, col_L8, coeff,
                                         spat_prev);
        const unsigned short* xenc_next =
            xenc + (size_t)((t < TT - 1) ? t + 1 : t) * NN * 64;
        k_node<<<NN / 32, 64, 0, stream>>>(t < TT - 1, recv, sentb, xenc_t, h_x, hx_bf,
                                           Bpn, gb_nb, x_sum,
                                           hid + (size_t)t * NN * 64,
                                           time_d + (size_t)t * NN * 64,
                                           xenc_next, Bpu, usr);
    }
    // final lap for t = TT-1
    k_glap<<<GBl, 256, 0, stream>>>(0, h_e, row_r, row_s, col_s2r,
                                    recv, sentb, hx_bf, row_L, col_L8, coeff,
                                    spat_d + (size_t)(TT - 1) * NN * 64);
    k_dec<<<TT * NN / 128, 256, 0, stream>>>(hid, Bpd, b_d1, W_d2, b_d2,
                                             b_i1, W_i2, b_i2, out_nodes, pred_in);
}

// Round 17
// 625.045 us; speedup vs baseline: 1.0516x; 1.0516x over previous
//
#include <hip/hip_runtime.h>

#define TT 4
#define NN 20000
#define EE 320000
#define NZ 340000
#define NBKT 2500  // NN/8 per XCD bucket
#define SCB 2048   // scatter blocks fused into edge(t=0)
#define CNTB 2048  // bucketed count blocks in k_setup

typedef __attribute__((ext_vector_type(8))) __bf16 bf16x8;
typedef __attribute__((ext_vector_type(16))) float f32x16;

__device__ __forceinline__ unsigned short f2bf(float f) {
    unsigned int u = __float_as_uint(f);
    u = (u + 0x7FFFu + ((u >> 16) & 1u)) >> 16;
    return (unsigned short)u;
}
__device__ __forceinline__ float bf2f(unsigned short h) {
    return __uint_as_float(((unsigned int)h) << 16);
}

#define GLL16(src, dst) __builtin_amdgcn_global_load_lds( \
    (const __attribute__((address_space(1))) unsigned int*)(src), \
    (__attribute__((address_space(3))) unsigned int*)(dst), 16, 0, 0)

// ---------------- fused setup: bucketed CSR count + weight pack + xenc ----------------
#define XB (TT * NN / 4)

__global__ __launch_bounds__(256) void k_setup(
    const float* __restrict__ na, const float* __restrict__ W_ne,
    const float* __restrict__ b_ne, unsigned short* __restrict__ xenc,
    const int* __restrict__ r, const int* __restrict__ s,
    const int* __restrict__ Li, int* cnt_r, int* cnt_s, int* cnt_L,
    const float* __restrict__ W_eb, const float* __restrict__ W_nb,
    const float* __restrict__ W_d1, const float* __restrict__ W_i1,
    const float* __restrict__ emb, unsigned short* __restrict__ Bpe,
    unsigned short* __restrict__ Bpu, unsigned short* __restrict__ Bpn,
    unsigned short* __restrict__ Bpd, unsigned short* __restrict__ emb_bf) {
    int bid = blockIdx.x;
    if (bid < CNTB) {
        // XCD-bucketed count: cnt lines for this bucket stay in one XCD's L2.
        const int bucket = bid & 7;
        const int nlo = bucket * NBKT;
        const int cid = bid >> 3;
        const int stride = (CNTB >> 3) * 256;
        for (int i = cid * 256 + threadIdx.x; i < EE; i += stride) {
            int rv = r[i];
            if ((unsigned)(rv - nlo) < (unsigned)NBKT) atomicAdd(&cnt_r[rv], 1);
            int sv = s[i];
            if ((unsigned)(sv - nlo) < (unsigned)NBKT) atomicAdd(&cnt_s[sv], 1);
        }
        for (int i = cid * 256 + threadIdx.x; i < NZ; i += stride) {
            int lv = Li[i];
            if ((unsigned)(lv - nlo) < (unsigned)NBKT) atomicAdd(&cnt_L[lv], 1);
        }
        return;
    }
    bid -= CNTB;
    if (bid < 96) {
        int t = bid * 256 + threadIdx.x;
        if (t < 2 * 8 * 512) {
            int i = t & 7, l = (t >> 3) & 63, kb = (t >> 9) & 7, ch = t >> 12;
            int colv = ch * 32 + (l & 31);
            int k = kb * 16 + (l >> 5) * 8 + i;
            Bpe[t] = f2bf(W_eb[k * 64 + colv]);
        }
        if (t < 4 * 8 * 512) {
            int i = t & 7, l = (t >> 3) & 63, kb = (t >> 9) & 7, g = t >> 12;
            int colv = (g & 1) * 32 + (l & 31);
            int k = 128 + (g >> 1) * 128 + kb * 16 + (l >> 5) * 8 + i;
            Bpu[t] = f2bf(W_eb[k * 64 + colv]);
        }
        if (t < 2 * 16 * 512) {
            int i = t & 7, l = (t >> 3) & 63, kb = (t >> 9) % 16, ch = t / (16 * 512);
            int colv = ch * 32 + (l & 31);
            int k = kb * 16 + (l >> 5) * 8 + i;
            Bpn[t] = f2bf(W_nb[k * 64 + colv]);
        }
        if (t < 4 * 4 * 512) {
            int i = t & 7, l = (t >> 3) & 63, kb = (t >> 9) & 3, sec = t >> 11;
            int colv = (sec & 1) * 32 + (l & 31);
            int k = kb * 16 + (l >> 5) * 8 + i;
            const float* W = (sec < 2) ? W_d1 : W_i1;
            Bpd[t] = f2bf(W[k * 64 + colv]);
        }
        if (t < 100 * 64) emb_bf[t] = f2bf(emb[t]);
        return;
    }
    bid -= 96;
    int row = bid * 4 + (threadIdx.x >> 6);
    int j = threadIdx.x & 63;
    float4 a = *(const float4*)&na[(size_t)row * 4];
    float v = b_ne[j] + a.x * W_ne[j] + a.y * W_ne[64 + j] + a.z * W_ne[128 + j] + a.w * W_ne[192 + j];
    xenc[(size_t)row * 64 + j] = f2bf(fmaxf(v, 0.f));
}

__global__ __launch_bounds__(1024) void k_scan(int* cnt, int* rowp, int* wp) {
    int which = blockIdx.x;
    int* c = cnt + which * NN;
    int* row = rowp + which * (NN + 1);
    int* w = wp + which * NN;
    __shared__ int ssum[1024];
    int tid = threadIdx.x;
    const int CH = (NN + 1023) / 1024;
    int base = tid * CH;
    int s = 0;
    for (int i = 0; i < CH; ++i) { int idx = base + i; s += (idx < NN) ? c[idx] : 0; }
    ssum[tid] = s;
    __syncthreads();
    for (int o = 1; o < 1024; o <<= 1) {
        int v = (tid >= o) ? ssum[tid - o] : 0;
        __syncthreads();
        ssum[tid] += v;
        __syncthreads();
    }
    int run = (tid > 0) ? ssum[tid - 1] : 0;
    for (int i = 0; i < CH; ++i) {
        int idx = base + i;
        if (idx < NN) { row[idx] = run; w[idx] = run; run += c[idx]; }
    }
    if (tid == 1023) row[NN] = ssum[1023];
}

// ---------------- gbias-only kernel (t>=1): global-block update + bias fold ----------
__global__ __launch_bounds__(64) void k_gbias(
    const float* __restrict__ W_gb, const float* __restrict__ b_gb,
    const float* __restrict__ W_eb, const float* __restrict__ b_eb,
    const float* __restrict__ W_nb, const float* __restrict__ b_nb,
    float* __restrict__ g_cur, float* __restrict__ e_sum, float* __restrict__ x_sum,
    float* __restrict__ gb_eb, float* __restrict__ gb_nb) {
    int j = threadIdx.x;
    float a = b_gb[j];
    for (int k = 0; k < 64; ++k) a += (e_sum[k] / (float)EE) * W_gb[k * 64 + j];
    for (int k = 0; k < 64; ++k) a += (x_sum[k] / (float)NN) * W_gb[(64 + k) * 64 + j];
    for (int k = 0; k < 64; ++k) a += g_cur[k] * W_gb[(128 + k) * 64 + j];
    float gv = fmaxf(a, 0.f);
    g_cur[j] = gv;
    e_sum[j] = 0.f;
    x_sum[j] = 0.f;
    float a1 = b_eb[j], a2 = b_nb[j];
    for (int k = 0; k < 64; ++k) {
        float gk = __shfl(gv, k, 64);
        a1 = fmaf(gk, W_eb[(384 + k) * 64 + j], a1);
        a2 = fmaf(gk, W_nb[(256 + k) * 64 + j], a2);
    }
    gb_eb[j] = a1;
    gb_nb[j] = a2;
}

// ---------------- usr(t=0) standalone (+ gbias fold, no update, in block 0) --------
__global__ __launch_bounds__(64) void k_usr(
    const unsigned short* __restrict__ xenc_t, const unsigned short* __restrict__ hx_bf,
    const unsigned short* __restrict__ Bpu, unsigned int* __restrict__ usr,
    const float* __restrict__ W_eb, const float* __restrict__ b_eb,
    const float* __restrict__ W_nb, const float* __restrict__ b_nb,
    float* __restrict__ g_cur, float* __restrict__ gb_eb, float* __restrict__ gb_nb) {
    const int ln = threadIdx.x;
    const int er = ln & 31, hi = ln >> 5;

    if (blockIdx.x == 0) {
        int j = ln;
        float gv = g_cur[j];
        float a1 = b_eb[j], a2 = b_nb[j];
        for (int k = 0; k < 64; ++k) {
            float gk = __shfl(gv, k, 64);
            a1 = fmaf(gk, W_eb[(384 + k) * 64 + j], a1);
            a2 = fmaf(gk, W_nb[(256 + k) * 64 + j], a2);
        }
        gb_eb[j] = a1;
        gb_nb[j] = a2;
    }

    const int n0 = blockIdx.x * 32;
    const int n = n0 + er;

    f32x16 a0, a1, a2, a3;
    #pragma unroll
    for (int i = 0; i < 16; ++i) { a0[i] = 0.f; a1[i] = 0.f; a2[i] = 0.f; a3[i] = 0.f; }

    const unsigned short* sx = xenc_t + (size_t)64 * n + hi * 8;
    const unsigned short* sh = hx_bf + (size_t)64 * n + hi * 8;
    #pragma unroll
    for (int c = 0; c < 2; ++c) {
        const unsigned short* src = c ? sh : sx;
        #pragma unroll
        for (int kb = 0; kb < 4; ++kb) {
            bf16x8 a = *(const bf16x8*)(src + kb * 16);
            int kg = c * 4 + kb;
            bf16x8 b0 = *(const bf16x8*)&Bpu[(size_t)((0 * 8 + kg) * 64 + ln) * 8];
            bf16x8 b1 = *(const bf16x8*)&Bpu[(size_t)((1 * 8 + kg) * 64 + ln) * 8];
            bf16x8 b2 = *(const bf16x8*)&Bpu[(size_t)((2 * 8 + kg) * 64 + ln) * 8];
            bf16x8 b3 = *(const bf16x8*)&Bpu[(size_t)((3 * 8 + kg) * 64 + ln) * 8];
            a0 = __builtin_amdgcn_mfma_f32_32x32x16_bf16(a, b0, a0, 0, 0, 0);
            a1 = __builtin_amdgcn_mfma_f32_32x32x16_bf16(a, b1, a1, 0, 0, 0);
            a2 = __builtin_amdgcn_mfma_f32_32x32x16_bf16(a, b2, a2, 0, 0, 0);
            a3 = __builtin_amdgcn_mfma_f32_32x32x16_bf16(a, b3, a3, 0, 0, 0);
        }
    }
    #pragma unroll
    for (int r = 0; r < 16; ++r) {
        int row = (r & 3) + 8 * (r >> 2) + 4 * hi;
        size_t o = (size_t)(n0 + row) * 64;
        usr[o + er]      = (unsigned int)f2bf(a0[r]) | ((unsigned int)f2bf(a1[r]) << 16);
        usr[o + 32 + er] = (unsigned int)f2bf(a2[r]) | ((unsigned int)f2bf(a3[r]) << 16);
    }
}

// ---------------- edge block (+ fused scatter at t=0); epilogue usr gathers --------
__global__ __launch_bounds__(512) void k_edge(
    int first, int scatterb, unsigned short* __restrict__ h_e,
    const unsigned short* __restrict__ emb_bf,
    const unsigned int* __restrict__ usr, const int* __restrict__ eattr_t,
    const int* __restrict__ sidx, const int* __restrict__ ridx,
    const unsigned short* __restrict__ Bp, const float* __restrict__ gbias,
    float* __restrict__ e_sum,
    const int* __restrict__ Li, const int* __restrict__ Lj,
    const float* __restrict__ Lv,
    int* wp_r, int* wp_s, int* wp_L,
    int* col_r, int* col_s, uint2* col_L8) {
    __shared__ unsigned short sBe[8192];
    __shared__ float sRed[8][64];
    const int tid = threadIdx.x;

    if ((int)blockIdx.x < scatterb) {
        const int sbid = blockIdx.x;
        const int bucket = sbid & 7;
        const int nlo = bucket * NBKT;
        const int cid = sbid >> 3;
        const int stride = (scatterb >> 3) * 512;
        for (int i = cid * 512 + tid; i < EE; i += stride) {
            int rv = ridx[i];
            if ((unsigned)(rv - nlo) < (unsigned)NBKT)
                col_r[atomicAdd(&wp_r[rv], 1)] = i;
            int sv = sidx[i];
            if ((unsigned)(sv - nlo) < (unsigned)NBKT)
                col_s[atomicAdd(&wp_s[sv], 1)] = i;
        }
        for (int i = cid * 512 + tid; i < NZ; i += stride) {
            int lv = Li[i];
            if ((unsigned)(lv - nlo) < (unsigned)NBKT) {
                int pos = atomicAdd(&wp_L[lv], 1);
                uint2 v;
                v.x = (unsigned int)Lj[i];
                v.y = __float_as_uint(Lv[i]);
                col_L8[pos] = v;
            }
        }
        return;
    }

    const int w = tid >> 6, ln = tid & 63;
    const int er = ln & 31, hi = ln >> 5;
    const int ebase = ((int)blockIdx.x - scatterb) * 256 + w * 32;
    const int e = ebase + er;

    const int siv = sidx[ebase + er];
    const int riv = ridx[ebase + er];
    const int ai = eattr_t[e];

    #pragma unroll
    for (int i = 0; i < 2; ++i) {
        int off = i * 4096 + w * 512;
        GLL16(Bp + off + ln * 8, sBe + off);
    }

    const unsigned short* s0 = emb_bf + (size_t)64 * ai + hi * 8;
    const unsigned short* s1 = h_e + (size_t)64 * e + hi * 8;
    bf16x8 a0 = *(const bf16x8*)(s0);
    bf16x8 a1 = *(const bf16x8*)(s0 + 16);
    bf16x8 a2 = *(const bf16x8*)(s0 + 32);
    bf16x8 a3 = *(const bf16x8*)(s0 + 48);
    bf16x8 a4{}, a5{}, a6{}, a7{};
    if (!first) {
        a4 = *(const bf16x8*)(s1);
        a5 = *(const bf16x8*)(s1 + 16);
        a6 = *(const bf16x8*)(s1 + 32);
        a7 = *(const bf16x8*)(s1 + 48);
    }

    f32x16 acc0, acc1;
    #pragma unroll
    for (int i = 0; i < 16; ++i) { acc0[i] = 0.f; acc1[i] = 0.f; }

    __syncthreads();

    #define EMM(AF, KG)                                                              \
        {                                                                            \
            bf16x8 b0 = *(const bf16x8*)&sBe[(((KG)) * 64 + ln) * 8];                \
            bf16x8 b1 = *(const bf16x8*)&sBe[((8 + (KG)) * 64 + ln) * 8];            \
            acc0 = __builtin_amdgcn_mfma_f32_32x32x16_bf16(AF, b0, acc0, 0, 0, 0);   \
            acc1 = __builtin_amdgcn_mfma_f32_32x32x16_bf16(AF, b1, acc1, 0, 0, 0);   \
        }
    EMM(a0, 0) EMM(a1, 1) EMM(a2, 2) EMM(a3, 3)
    if (!first) {
        EMM(a4, 4) EMM(a5, 5) EMM(a6, 6) EMM(a7, 7)
    }
    #undef EMM

    const float gb0 = gbias[er], gb1 = gbias[er + 32];
    float cs0 = 0.f, cs1 = 0.f;
    #pragma unroll
    for (int r = 0; r < 16; ++r) {
        int row = (r & 3) + 8 * (r >> 2) + 4 * hi;
        int si_row = __shfl(siv, row, 64);
        int ri_row = __shfl(riv, row, 64);
        unsigned int us = usr[(size_t)si_row * 64 + er];
        unsigned int ur = usr[(size_t)ri_row * 64 + 32 + er];
        size_t o = (size_t)(ebase + row) * 64;
        float v0 = fmaxf(acc0[r] + bf2f((unsigned short)(us & 0xFFFF))
                                 + bf2f((unsigned short)(ur & 0xFFFF)) + gb0, 0.f);
        float v1 = fmaxf(acc1[r] + bf2f((unsigned short)(us >> 16))
                                 + bf2f((unsigned short)(ur >> 16)) + gb1, 0.f);
        cs0 += v0; cs1 += v1;
        h_e[o + er] = f2bf(v0);
        h_e[o + er + 32] = f2bf(v1);
    }
    cs0 += __shfl_xor(cs0, 32, 64);
    cs1 += __shfl_xor(cs1, 32, 64);
    if (hi == 0) { sRed[w][er] = cs0; sRed[w][er + 32] = cs1; }
    __syncthreads();
    if (w == 0) {
        float t = 0.f;
        #pragma unroll
        for (int q = 0; q < 8; ++q) t += sRed[q][ln];
        atomicAdd(&e_sum[ln], t);
    }
}

// ---------------- fused gather(t) [64 thr/node, half-split] + lap(t-1) ----------------
__global__ __launch_bounds__(256) void k_glap(
    int gatherb,
    const unsigned short* __restrict__ h_e, const int* __restrict__ row_r,
    const int* __restrict__ col_r, const int* __restrict__ row_s,
    const int* __restrict__ col_s, unsigned short* __restrict__ recv,
    unsigned short* __restrict__ sentb,
    const unsigned short* __restrict__ hx_bf, const int* __restrict__ row_L,
    const uint2* __restrict__ col_L8, const float* __restrict__ coeff,
    float* __restrict__ spat_prev) {
    if ((int)blockIdx.x < gatherb) {
        int t = blockIdx.x * 256 + threadIdx.x;
        int sub = t & 63, n = t >> 6;
        int g = sub & 15, which = (sub >> 4) & 1, half = sub >> 5;
        const int* rowp = which ? row_s : row_r;
        const int* colp = which ? col_s : col_r;
        unsigned short* outp = which ? sentb : recv;

        float a0 = 0.f, a1 = 0.f, a2 = 0.f, a3 = 0.f;
        int b0 = rowp[n], b1 = rowp[n + 1];
        int mid = b0 + ((b1 - b0) >> 1);
        int p0 = half ? mid : b0;
        int p1 = half ? b1 : mid;
        for (int p = p0; p < p1; ++p) {
            uint2 v = *(const uint2*)&h_e[(size_t)64 * colp[p] + g * 4];
            a0 += bf2f((unsigned short)(v.x & 0xFFFF));
            a1 += bf2f((unsigned short)(v.x >> 16));
            a2 += bf2f((unsigned short)(v.y & 0xFFFF));
            a3 += bf2f((unsigned short)(v.y >> 16));
        }
        a0 += __shfl_xor(a0, 32, 64);
        a1 += __shfl_xor(a1, 32, 64);
        a2 += __shfl_xor(a2, 32, 64);
        a3 += __shfl_xor(a3, 32, 64);
        if (half == 0) {
            uint2 packed;
            packed.x = (unsigned int)f2bf(a0) | ((unsigned int)f2bf(a1) << 16);
            packed.y = (unsigned int)f2bf(a2) | ((unsigned int)f2bf(a3) << 16);
            *(uint2*)&outp[(size_t)64 * n + g * 4] = packed;
        }
        return;
    }
    int t = ((int)blockIdx.x - gatherb) * 256 + threadIdx.x;
    int sub = t & 31, n = t >> 5;
    int g = sub & 15, half = sub >> 4;
    float a0 = 0.f, a1 = 0.f, a2 = 0.f, a3 = 0.f;
    int b0 = row_L[n], b1 = row_L[n + 1];
    int mid = b0 + ((b1 - b0) >> 1);
    int p0 = half ? mid : b0;
    int p1 = half ? b1 : mid;
    for (int p = p0; p < p1; ++p) {
        uint2 e = col_L8[p];
        float lv = __uint_as_float(e.y);
        uint2 hv = *(const uint2*)&hx_bf[(size_t)64 * e.x + g * 4];
        a0 = fmaf(lv, bf2f((unsigned short)(hv.x & 0xFFFF)), a0);
        a1 = fmaf(lv, bf2f((unsigned short)(hv.x >> 16)), a1);
        a2 = fmaf(lv, bf2f((unsigned short)(hv.y & 0xFFFF)), a2);
        a3 = fmaf(lv, bf2f((unsigned short)(hv.y >> 16)), a3);
    }
    a0 += __shfl_xor(a0, 16, 64);
    a1 += __shfl_xor(a1, 16, 64);
    a2 += __shfl_xor(a2, 16, 64);
    a3 += __shfl_xor(a3, 16, 64);
    if (half == 0) {
        float c = coeff[0];
        float4 outv = {c * a0, c * a1, c * a2, c * a3};
        *(float4*)&spat_prev[(size_t)64 * n + g * 4] = outv;
    }
}

// ---------------- node block + fused usr(t+1) via swizzled LDS hx tile ----------------
#define NODE_CHUNK(CIDX, BASE)                                                          \
    {                                                                                   \
        const unsigned short* src = (BASE) + hi * 8;                                    \
        _Pragma("unroll") for (int kb = 0; kb < 4; ++kb) {                              \
            bf16x8 a = *(const bf16x8*)(src + kb * 16);                                 \
            bf16x8 b0 = *(const bf16x8*)&Bp[(size_t)(((CIDX)*4 + kb) * 64 + ln) * 8];   \
            bf16x8 b1 = *(const bf16x8*)&Bp[(size_t)((16 + (CIDX)*4 + kb) * 64 + ln) * 8]; \
            acc0 = __builtin_amdgcn_mfma_f32_32x32x16_bf16(a, b0, acc0, 0, 0, 0);       \
            acc1 = __builtin_amdgcn_mfma_f32_32x32x16_bf16(a, b1, acc1, 0, 0, 0);       \
        }                                                                               \
    }

__global__ __launch_bounds__(64) void k_node(
    int has_next,
    const unsigned short* __restrict__ recv, const unsigned short* __restrict__ sentb,
    const unsigned short* __restrict__ xenc_t, float* __restrict__ h_x,
    unsigned short* __restrict__ hx_bf, const unsigned short* __restrict__ Bp,
    const float* __restrict__ gbias, float* __restrict__ x_sum,
    unsigned short* __restrict__ hid_t, float* __restrict__ timed_t,
    const unsigned short* __restrict__ xenc_next,
    const unsigned short* __restrict__ Bpu, unsigned int* __restrict__ usr) {
    __shared__ unsigned short sHx[32 * 64];
    const int ln = threadIdx.x;
    const int er = ln & 31, hi = ln >> 5;
    const int n0 = blockIdx.x * 32;
    const int n = n0 + er;

    f32x16 acc0, acc1;
    #pragma unroll
    for (int i = 0; i < 16; ++i) { acc0[i] = 0.f; acc1[i] = 0.f; }

    NODE_CHUNK(0, recv + (size_t)64 * n)
    NODE_CHUNK(1, sentb + (size_t)64 * n)
    NODE_CHUNK(2, xenc_t + (size_t)64 * n)
    NODE_CHUNK(3, hx_bf + (size_t)64 * n)

    const float gb0 = gbias[er], gb1 = gbias[er + 32];
    const int g0 = er >> 3, w0 = er & 7;
    float cs0 = 0.f, cs1 = 0.f;
    #pragma unroll
    for (int r = 0; r < 16; ++r) {
        int row = (r & 3) + 8 * (r >> 2) + 4 * hi;
        size_t o = (size_t)(n0 + row) * 64;
        float x0 = fmaxf(acc0[r] + gb0, 0.f);
        float x1 = fmaxf(acc1[r] + gb1, 0.f);
        cs0 += x0; cs1 += x1;
        float hx0 = h_x[o + er] + x0;
        float hx1 = h_x[o + er + 32] + x1;
        unsigned short hb0 = f2bf(hx0), hb1 = f2bf(hx1);
        h_x[o + er] = hx0;        h_x[o + er + 32] = hx1;
        hx_bf[o + er] = hb0;      hx_bf[o + er + 32] = hb1;
        hid_t[o + er] = hb0;      hid_t[o + er + 32] = hb1;
        timed_t[o + er] = x0;     timed_t[o + er + 32] = x1;
        int rs = row & 7;
        sHx[row * 64 + (((g0 ^ rs) << 3) | w0)] = hb0;
        sHx[row * 64 + ((((g0 + 4) ^ rs) << 3) | w0)] = hb1;
    }
    cs0 += __shfl_xor(cs0, 32, 64);
    cs1 += __shfl_xor(cs1, 32, 64);
    if (hi == 0) {
        atomicAdd(&x_sum[er], cs0);
        atomicAdd(&x_sum[er + 32], cs1);
    }
    if (!has_next) return;

    __syncthreads();

    f32x16 a0, a1, a2, a3;
    #pragma unroll
    for (int i = 0; i < 16; ++i) { a0[i] = 0.f; a1[i] = 0.f; a2[i] = 0.f; a3[i] = 0.f; }

    const unsigned short* sx = xenc_next + (size_t)64 * n + hi * 8;
    #pragma unroll
    for (int c = 0; c < 2; ++c) {
        #pragma unroll
        for (int kb = 0; kb < 4; ++kb) {
            bf16x8 a;
            if (c == 0) {
                a = *(const bf16x8*)(sx + kb * 16);
            } else {
                int gi = hi + 2 * kb;
                a = *(const bf16x8*)&sHx[er * 64 + ((gi ^ (er & 7)) << 3)];
            }
            int kg = c * 4 + kb;
            bf16x8 b0 = *(const bf16x8*)&Bpu[(size_t)((0 * 8 + kg) * 64 + ln) * 8];
            bf16x8 b1 = *(const bf16x8*)&Bpu[(size_t)((1 * 8 + kg) * 64 + ln) * 8];
            bf16x8 b2 = *(const bf16x8*)&Bpu[(size_t)((2 * 8 + kg) * 64 + ln) * 8];
            bf16x8 b3 = *(const bf16x8*)&Bpu[(size_t)((3 * 8 + kg) * 64 + ln) * 8];
            a0 = __builtin_amdgcn_mfma_f32_32x32x16_bf16(a, b0, a0, 0, 0, 0);
            a1 = __builtin_amdgcn_mfma_f32_32x32x16_bf16(a, b1, a1, 0, 0, 0);
            a2 = __builtin_amdgcn_mfma_f32_32x32x16_bf16(a, b2, a2, 0, 0, 0);
            a3 = __builtin_amdgcn_mfma_f32_32x32x16_bf16(a, b3, a3, 0, 0, 0);
        }
    }
    #pragma unroll
    for (int r = 0; r < 16; ++r) {
        int row = (r & 3) + 8 * (r >> 2) + 4 * hi;
        size_t o = (size_t)(n0 + row) * 64;
        usr[o + er]      = (unsigned int)f2bf(a0[r]) | ((unsigned int)f2bf(a1[r]) << 16);
        usr[o + 32 + er] = (unsigned int)f2bf(a2[r]) | ((unsigned int)f2bf(a3[r]) << 16);
    }
}

// ---------------- decoders: MFMA layer1, LDS transpose, scalar layer2 ----------------
__global__ __launch_bounds__(256) void k_dec(
    const unsigned short* __restrict__ hid_bf, const unsigned short* __restrict__ Bpd,
    const float* __restrict__ b_d1, const float* __restrict__ W_d2,
    const float* __restrict__ b_d2, const float* __restrict__ b_i1,
    const float* __restrict__ W_i2, const float* __restrict__ b_i2,
    float* __restrict__ out_nodes, float* __restrict__ pred_in) {
    __shared__ unsigned short sDec[4][32 * 138];
    const int tid = threadIdx.x;
    const int w = tid >> 6, ln = tid & 63;
    const int er = ln & 31, hi = ln >> 5;
    const int row0 = (blockIdx.x * 4 + w) * 32;

    f32x16 ad0, ad1, ai0, ai1;
    #pragma unroll
    for (int i = 0; i < 16; ++i) { ad0[i] = 0.f; ad1[i] = 0.f; ai0[i] = 0.f; ai1[i] = 0.f; }

    const unsigned short* src = hid_bf + (size_t)(row0 + er) * 64 + hi * 8;
    #pragma unroll
    for (int kb = 0; kb < 4; ++kb) {
        bf16x8 a = *(const bf16x8*)(src + kb * 16);
        bf16x8 bd0 = *(const bf16x8*)&Bpd[((0 * 4 + kb) * 64 + ln) * 8];
        bf16x8 bd1 = *(const bf16x8*)&Bpd[((4 + kb) * 64 + ln) * 8];
        bf16x8 bi0 = *(const bf16x8*)&Bpd[((8 + kb) * 64 + ln) * 8];
        bf16x8 bi1 = *(const bf16x8*)&Bpd[((12 + kb) * 64 + ln) * 8];
        ad0 = __builtin_amdgcn_mfma_f32_32x32x16_bf16(a, bd0, ad0, 0, 0, 0);
        ad1 = __builtin_amdgcn_mfma_f32_32x32x16_bf16(a, bd1, ad1, 0, 0, 0);
        ai0 = __builtin_amdgcn_mfma_f32_32x32x16_bf16(a, bi0, ai0, 0, 0, 0);
        ai1 = __builtin_amdgcn_mfma_f32_32x32x16_bf16(a, bi1, ai1, 0, 0, 0);
    }

    const float bd0v = b_d1[er], bd1v = b_d1[er + 32];
    const float bi0v = b_i1[er], bi1v = b_i1[er + 32];
    unsigned short* sw = &sDec[w][0];
    #pragma unroll
    for (int r = 0; r < 16; ++r) {
        int row = (r & 3) + 8 * (r >> 2) + 4 * hi;
        sw[row * 138 + er]       = f2bf(fmaxf(ad0[r] + bd0v, 0.f));
        sw[row * 138 + er + 32]  = f2bf(fmaxf(ad1[r] + bd1v, 0.f));
        sw[row * 138 + er + 64]  = f2bf(fmaxf(ai0[r] + bi0v, 0.f));
        sw[row * 138 + er + 96]  = f2bf(fmaxf(ai1[r] + bi1v, 0.f));
    }
    __syncthreads();

    const int g_row = row0 + er;
    if (hi == 0) {
        float s = 0.f;
        for (int k = 0; k < 32; ++k) {
            unsigned int u = *(const unsigned int*)&sw[er * 138 + 2 * k];
            s = fmaf(bf2f((unsigned short)(u & 0xFFFF)), W_d2[2 * k], s);
            s = fmaf(bf2f((unsigned short)(u >> 16)), W_d2[2 * k + 1], s);
        }
        out_nodes[g_row] = s + b_d2[0];
    } else {
        float s0 = 0.f, s1 = 0.f, s2 = 0.f, s3 = 0.f;
        for (int k = 0; k < 32; ++k) {
            unsigned int u = *(const unsigned int*)&sw[er * 138 + 64 + 2 * k];
            float vlo = bf2f((unsigned short)(u & 0xFFFF));
            float vhi = bf2f((unsigned short)(u >> 16));
            float4 w0 = *(const float4*)&W_i2[(2 * k) * 4];
            float4 w1 = *(const float4*)&W_i2[(2 * k + 1) * 4];
            s0 = fmaf(vlo, w0.x, fmaf(vhi, w1.x, s0));
            s1 = fmaf(vlo, w0.y, fmaf(vhi, w1.y, s1));
            s2 = fmaf(vlo, w0.z, fmaf(vhi, w1.z, s2));
            s3 = fmaf(vlo, w0.w, fmaf(vhi, w1.w, s3));
        }
        float4 pv = {s0 + b_i2[0], s1 + b_i2[1], s2 + b_i2[2], s3 + b_i2[3]};
        *(float4*)&pred_in[(size_t)4 * g_row] = pv;
    }
}

extern "C" void kernel_launch(void* const* d_in, const int* in_sizes, int n_in,
                              void* d_out, int out_size, void* d_ws, size_t ws_size,
                              hipStream_t stream) {
    (void)in_sizes; (void)n_in; (void)out_size; (void)ws_size;
    const float* node_attr   = (const float*)d_in[0];
    const float* global_attr = (const float*)d_in[1];
    const float* L_values    = (const float*)d_in[2];
    const float* coeff       = (const float*)d_in[3];
    const int*   edge_attr   = (const int*)d_in[4];
    const int*   edge_index  = (const int*)d_in[5];
    const int*   L_index     = (const int*)d_in[6];
    const float* emb  = (const float*)d_in[8];
    const float* W_ne = (const float*)d_in[9];
    const float* b_ne = (const float*)d_in[10];
    const float* W_eb = (const float*)d_in[11];
    const float* b_eb = (const float*)d_in[12];
    const float* W_nb = (const float*)d_in[13];
    const float* b_nb = (const float*)d_in[14];
    const float* W_gb = (const float*)d_in[15];
    const float* b_gb = (const float*)d_in[16];
    const float* W_d1 = (const float*)d_in[17];
    const float* b_d1 = (const float*)d_in[18];
    const float* W_d2 = (const float*)d_in[19];
    const float* b_d2 = (const float*)d_in[20];
    const float* W_i1 = (const float*)d_in[21];
    const float* b_i1 = (const float*)d_in[22];
    const float* W_i2 = (const float*)d_in[23];
    const float* b_i2 = (const float*)d_in[24];

    const int* s_idx = edge_index;
    const int* r_idx = edge_index + EE;
    const int* Li = L_index;
    const int* Lj = L_index + NZ;

    char* ws = (char*)d_ws;
    size_t off = 0;
    auto alloc = [&](size_t bytes) -> void* {
        void* p = ws + off;
        off = (off + bytes + 255) & ~(size_t)255;
        return p;
    };
    unsigned short* xenc   = (unsigned short*)alloc((size_t)TT * NN * 64 * 2);
    unsigned short* hid    = (unsigned short*)alloc((size_t)TT * NN * 64 * 2);
    float*          h_x    = (float*)alloc((size_t)NN * 64 * 4);
    unsigned short* hx_bf  = (unsigned short*)alloc((size_t)NN * 64 * 2);
    unsigned short* h_e    = (unsigned short*)alloc((size_t)EE * 64 * 2);
    unsigned short* recv   = (unsigned short*)alloc((size_t)NN * 64 * 2);
    unsigned short* sentb  = (unsigned short*)alloc((size_t)NN * 64 * 2);
    unsigned int*   usr    = (unsigned int*)alloc((size_t)NN * 64 * 4);
    float* smalls          = (float*)alloc(2048);
    unsigned short* Bpe    = (unsigned short*)alloc((size_t)2 * 8 * 512 * 2);
    unsigned short* Bpu    = (unsigned short*)alloc((size_t)4 * 8 * 512 * 2);
    unsigned short* Bpn    = (unsigned short*)alloc((size_t)2 * 16 * 512 * 2);
    unsigned short* Bpd    = (unsigned short*)alloc((size_t)4 * 4 * 512 * 2);
    unsigned short* emb_bf = (unsigned short*)alloc((size_t)100 * 64 * 2);
    int* cnt    = (int*)alloc((size_t)3 * NN * 4);
    int* rowp   = (int*)alloc((size_t)3 * (NN + 1) * 4);
    int* wp     = (int*)alloc((size_t)3 * NN * 4);
    int* col_r  = (int*)alloc((size_t)EE * 4);
    int* col_s  = (int*)alloc((size_t)EE * 4);
    uint2* col_L8 = (uint2*)alloc((size_t)NZ * 8);

    float* g_cur = smalls;
    float* e_sum = smalls + 64;
    float* x_sum = smalls + 128;
    float* gb_eb = smalls + 192;
    float* gb_nb = smalls + 256;
    int* cnt_r = cnt, *cnt_s = cnt + NN, *cnt_L = cnt + 2 * NN;
    int* row_r = rowp, *row_s = rowp + (NN + 1), *row_L = rowp + 2 * (NN + 1);
    int* wp_r = wp, *wp_s = wp + NN, *wp_L = wp + 2 * NN;

    float* out_nodes = (float*)d_out;                    // [T,N,1]
    float* time_d = out_nodes + (size_t)TT * NN;         // [T,N,64]
    float* spat_d = time_d + (size_t)TT * NN * 64;       // [T,N,64]
    float* pred_in = spat_d + (size_t)TT * NN * 64;      // [T,N,4]

    hipMemsetAsync(h_x, 0, (size_t)NN * 64 * 4, stream);
    hipMemsetAsync(hx_bf, 0, (size_t)NN * 64 * 2, stream);
    hipMemsetAsync(smalls, 0, 2048, stream);
    hipMemsetAsync(cnt, 0, (size_t)3 * NN * 4, stream);
    hipMemcpyAsync(g_cur, global_attr, 64 * 4, hipMemcpyDeviceToDevice, stream);

    k_setup<<<CNTB + 96 + XB, 256, 0, stream>>>(node_attr, W_ne, b_ne, xenc,
                                                r_idx, s_idx, Li, cnt_r, cnt_s, cnt_L,
                                                W_eb, W_nb, W_d1, W_i1, emb,
                                                Bpe, Bpu, Bpn, Bpd, emb_bf);
    k_scan<<<3, 1024, 0, stream>>>(cnt, rowp, wp);
    k_usr<<<NN / 32, 64, 0, stream>>>(xenc, hx_bf, Bpu, usr,
                                      W_eb, b_eb, W_nb, b_nb, g_cur, gb_eb, gb_nb);

    const int GBg = NN * 64 / 256;  // 5000 gather blocks (64 thr/node)
    const int GBl = NN * 32 / 256;  // 2500 lap blocks
    for (int t = 0; t < TT; ++t) {
        const unsigned short* xenc_t = xenc + (size_t)t * NN * 64;
        if (t > 0)
            k_gbias<<<1, 64, 0, stream>>>(W_gb, b_gb, W_eb, b_eb, W_nb, b_nb,
                                          g_cur, e_sum, x_sum, gb_eb, gb_nb);
        int scb = (t == 0) ? SCB : 0;
        k_edge<<<scb + EE / 256, 512, 0, stream>>>(
            t == 0, scb, h_e, emb_bf, usr,
            edge_attr + (size_t)t * EE, s_idx, r_idx, Bpe, gb_eb, e_sum,
            Li, Lj, L_values, wp_r, wp_s, wp_L, col_r, col_s, col_L8);
        int grid = GBg + ((t > 0) ? GBl : 0);
        float* spat_prev = spat_d + (size_t)((t > 0) ? t - 1 : 0) * NN * 64;
        k_glap<<<grid, 256, 0, stream>>>(GBg, h_e, row_r, col_r, row_s, col_s,
                                         recv, sentb, hx_bf, row_L, col_L8, coeff,
                                         spat_prev);
        const unsigned short* xenc_next =
            xenc + (size_t)((t < TT - 1) ? t + 1 : t) * NN * 64;
        k_node<<<NN / 32, 64, 0, stream>>>(t < TT - 1, recv, sentb, xenc_t, h_x, hx_bf,
                                           Bpn, gb_nb, x_sum,
                                           hid + (size_t)t * NN * 64,
                                           time_d + (size_t)t * NN * 64,
                                           xenc_next, Bpu, usr);
    }
    // final lap for t = TT-1
    k_glap<<<GBl, 256, 0, stream>>>(0, h_e, row_r, col_r, row_s, col_s,
                                    recv, sentb, hx_bf, row_L, col_L8, coeff,
                                    spat_d + (size_t)(TT - 1) * NN * 64);
    k_dec<<<TT * NN / 128, 256, 0, stream>>>(hid, Bpd, b_d1, W_d2, b_d2,
                                             b_i1, W_i2, b_i2, out_nodes, pred_in);
}